// Round 1
// baseline (279.787 us; speedup 1.0000x reference)
//
#include <hip/hip_runtime.h>
#include <math.h>

// CRF NLL: out[b] = logZ[b] - gold[b].  B=1024, L=512, T=64.
//
// R7: replace the 1-batch-per-block LDS-roundtrip recurrence (1050 cyc/step,
//   latency-bound at 2 waves/SIMD) with 16-batches-per-wave MFMA chains:
//   - mfma_f32_16x16x32_f16: A = exp(trans) in 8 constant reg fragments,
//     B = alpha (16 sequences), 8 MFMA per step (4 M-chunks x 2 K-chunks).
//   - logical-tag permutation lambda(c,m)=32(c>>1)+8(m>>2)+4(c&1)+(m&3) is
//     baked into the E fragments so each lane's 16 MFMA outputs ARE its next
//     B-fragment elements (B_kc[e] = a[8kc+e]): zero cross-lane ops per step.
//   - emissions: 4x float4 coalesced loads/step, 4-step register prefetch,
//     exp computed one step ahead (overlaps MFMA).
//   - renorm: power-of-2 scale from logical-tag-0 element (1 shfl), kacc.
//   - block = 4 waves: w0 fwd chain, w1 bwd chain, w2/w3 gold score.
//     64 blocks x 16 batches. f32->f16 packs use RTE (RTZ biases logZ).

#define TDIM 64
typedef _Float16 f16;
typedef _Float16 f16x2 __attribute__((ext_vector_type(2)));
typedef _Float16 f16x8 __attribute__((ext_vector_type(8)));
typedef float    f32x4 __attribute__((ext_vector_type(4)));

union B8 { f16x8 v; f16x2 p[4]; };

#define MFMA16(A, B, C) __builtin_amdgcn_mfma_f32_16x16x32_f16((A), (B), (C), 0, 0, 0)

// RTE f16 pair pack (v_cvt_f16_f32 x2 + pack; NOT cvt_pkrtz which is RTZ)
__device__ __forceinline__ f16x2 pk2(float a, float b) {
    f16x2 r; r[0] = (f16)a; r[1] = (f16)b; return r;
}

// One direction's 256-step chain over 16 batches.
// DIR=0: forward (t = 0..L/2-1, t=0 is init).  DIR=1: backward (t = L-1..L/2).
// Lane l: batch = bg + (l&15); holds logical tags lambda(c,4*(l>>4)+r).
template <int DIR>
__device__ __forceinline__ void run_chain(
    const float* __restrict__ lp,    // logits + (bg+ml)*L*64   (per-lane batch row base)
    const int*   __restrict__ mrow,  // mask   + (bg+ml)*L
    const float* __restrict__ trans,
    int L, int ml, int gl, bool masked,
    float a[16], int& kacc)
{
    // ---- constant A fragments: A_c,kc[m][k] = E(in = 32kc+k, out = lambda(c,m))
    f16x8 Af[4][2];
    #pragma unroll
    for (int c = 0; c < 4; ++c) {
        const int mlog = 32*(c>>1) + 8*(ml>>2) + 4*(c&1) + (ml&3);
        #pragma unroll
        for (int kc = 0; kc < 2; ++kc) {
            B8 t;
            #pragma unroll
            for (int e = 0; e < 8; e += 2) {
                const int k0 = 32*kc + 8*gl + e;
                float x0, x1;
                if (DIR == 0) { x0 = trans[k0*TDIM + mlog];  x1 = trans[(k0+1)*TDIM + mlog]; }
                else          { x0 = trans[mlog*TDIM + k0];  x1 = trans[mlog*TDIM + k0 + 1]; }
                t.p[e>>1] = pk2(__expf(x0), __expf(x1));
            }
            Af[c][kc] = t.v;
        }
    }

    #pragma unroll
    for (int i = 0; i < 16; ++i) a[i] = 1.f;   // bwd: z_{L-1}=1; fwd: dummy (t=0 init)
    kacc = 0;

    // per-lane emission offsets for logical tags lambda(c, 4*gl + r)
    const int xo0 = 8*gl, xo1 = 8*gl + 4, xo2 = 8*gl + 32, xo3 = 8*gl + 36;

    // ---- 4-step register prefetch of raw logits rows
    float4 Rf[4][4];
    #pragma unroll
    for (int u = 0; u < 4; ++u) {
        const int t = (DIR == 0) ? u : (L - 1 - u);
        const float* pt = lp + (size_t)t * TDIM;
        Rf[u][0] = *(const float4*)(pt + xo0);
        Rf[u][1] = *(const float4*)(pt + xo1);
        Rf[u][2] = *(const float4*)(pt + xo2);
        Rf[u][3] = *(const float4*)(pt + xo3);
    }

    // X for the first step (pipelined: step st consumes Xc, computes X(st+1))
    float Xc[16];
    #pragma unroll
    for (int c = 0; c < 4; ++c) {
        Xc[c*4+0] = __expf(Rf[0][c].x); Xc[c*4+1] = __expf(Rf[0][c].y);
        Xc[c*4+2] = __expf(Rf[0][c].z); Xc[c*4+3] = __expf(Rf[0][c].w);
    }

    const int NS = L >> 1;   // 256 steps
    for (int kb = 0; kb < NS/4; ++kb) {
        #pragma unroll
        for (int u = 0; u < 4; ++u) {
            const int st = 4*kb + u;
            const int t  = (DIR == 0) ? st : (L - 1 - st);

            float cand[16];
            if (DIR == 0 && st == 0) {
                // init: alpha_0 = exp(logits[:,0,:])
                #pragma unroll
                for (int i = 0; i < 16; ++i) cand[i] = Xc[i];
            } else {
                // B operand: fwd = alpha; bwd = z * X_t
                float bsrc[16];
                #pragma unroll
                for (int i = 0; i < 16; ++i) bsrc[i] = (DIR == 0) ? a[i] : a[i]*Xc[i];
                B8 b0, b1;
                #pragma unroll
                for (int h = 0; h < 4; ++h) {
                    b0.p[h] = pk2(bsrc[2*h],     bsrc[2*h+1]);
                    b1.p[h] = pk2(bsrc[8 + 2*h], bsrc[8 + 2*h+1]);
                }
                f32x4 D0 = {0.f,0.f,0.f,0.f}, D1 = {0.f,0.f,0.f,0.f};
                f32x4 D2 = {0.f,0.f,0.f,0.f}, D3 = {0.f,0.f,0.f,0.f};
                D0 = MFMA16(Af[0][0], b0.v, D0); D0 = MFMA16(Af[0][1], b1.v, D0);
                D1 = MFMA16(Af[1][0], b0.v, D1); D1 = MFMA16(Af[1][1], b1.v, D1);
                D2 = MFMA16(Af[2][0], b0.v, D2); D2 = MFMA16(Af[2][1], b1.v, D2);
                D3 = MFMA16(Af[3][0], b0.v, D3); D3 = MFMA16(Af[3][1], b1.v, D3);
                if (DIR == 0) {
                    #pragma unroll
                    for (int r = 0; r < 4; ++r) {
                        cand[r]      = D0[r] * Xc[r];
                        cand[4 + r]  = D1[r] * Xc[4 + r];
                        cand[8 + r]  = D2[r] * Xc[8 + r];
                        cand[12 + r] = D3[r] * Xc[12 + r];
                    }
                } else {
                    #pragma unroll
                    for (int r = 0; r < 4; ++r) {
                        cand[r] = D0[r]; cand[4+r] = D1[r];
                        cand[8+r] = D2[r]; cand[12+r] = D3[r];
                    }
                }
                if (masked) {               // generic fallback (mask==1 skips this)
                    const int m = mrow[t];  // per-batch, uniform across gl
                    #pragma unroll
                    for (int i = 0; i < 16; ++i) cand[i] = (m > 0) ? cand[i] : a[i];
                }
            }

            // prefetch raw logits for step st+4 into the slot just consumed
            {
                int sn = st + 4; if (sn >= NS) sn = st;
                const int tn = (DIR == 0) ? sn : (L - 1 - sn);
                const float* pn = lp + (size_t)tn * TDIM;
                Rf[u][0] = *(const float4*)(pn + xo0);
                Rf[u][1] = *(const float4*)(pn + xo1);
                Rf[u][2] = *(const float4*)(pn + xo2);
                Rf[u][3] = *(const float4*)(pn + xo3);
            }
            // exp for step st+1 (overlaps MFMA/renorm of this step)
            float Xn[16];
            {
                const int un = (u + 1) & 3;
                #pragma unroll
                for (int c = 0; c < 4; ++c) {
                    Xn[c*4+0] = __expf(Rf[un][c].x); Xn[c*4+1] = __expf(Rf[un][c].y);
                    Xn[c*4+2] = __expf(Rf[un][c].z); Xn[c*4+3] = __expf(Rf[un][c].w);
                }
            }

            // power-of-2 renorm: ref = logical tag 0 of this batch (lane ml, cand[0])
            {
                const float ref = __shfl(cand[0], ml);
                const int eb = (__float_as_int(ref) >> 23) & 255;
                const int kk = eb - 117;                         // target 2^-10
                kacc += kk;
                const float s = __int_as_float((unsigned)(244 - eb) << 23);  // 2^-kk
                #pragma unroll
                for (int i = 0; i < 16; ++i) a[i] = cand[i] * s;
            }
            #pragma unroll
            for (int i = 0; i < 16; ++i) Xc[i] = Xn[i];
        }
    }
}

__global__ __launch_bounds__(256, 1) void crf_mfma_kernel(
    const float* __restrict__ logits,  // [B, L, 64]
    const int*   __restrict__ tags,    // [B, L]
    const int*   __restrict__ mask,    // [B, L]
    const float* __restrict__ trans,   // [64, 64]
    float* __restrict__ out,           // [B]
    int L)
{
    const int tid = threadIdx.x;
    const int w   = tid >> 6;          // 0 fwd chain, 1 bwd chain, 2/3 gold
    const int l   = tid & 63;
    const int ml  = l & 15;            // batch within group
    const int gl  = l >> 4;            // lane group
    const int bg  = blockIdx.x * 16;
    const int bi  = bg + ml;

    __shared__ __align__(16) float zfin[64][16];   // bwd final state
    __shared__ float gpart2[2][16];
    __shared__ int   kbuf[16];

    float a[16];
    int   kacc = 0;

    if (w >= 2) {
        // ---------------- gold score, half [t0, t0+L/2) ----------------
        const int t0 = (w - 2) * (L >> 1);
        const int*   tb  = tags + (size_t)bi * L;
        const int*   mb  = mask + (size_t)bi * L;
        const float* lbg = logits + (size_t)bi * L * TDIM;
        float gs = 0.f;
        #pragma unroll 4
        for (int i = 0; i < (L >> 3); ++i) {       // L/2 positions / 4 lanes
            const int t  = t0 + gl + 4*i;
            const int tg = tb[t];
            const float mk = (float)mb[t];
            const float em = lbg[(size_t)t * TDIM + tg];
            const float tr = (t > 0) ? trans[tb[t-1] * TDIM + tg] : 0.f;
            gs += mk * (em + tr);
        }
        gs += __shfl_xor(gs, 16);
        gs += __shfl_xor(gs, 32);
        if (l < 16) gpart2[w - 2][l] = gs;
    } else {
        // ---------------- recurrence chains ----------------
        const float* lp   = logits + (size_t)bi * L * TDIM;
        const int*   mrow = mask + (size_t)bi * L;
        // fast-path detection: all-ones mask in this wave's half?
        const int t0 = (w == 0) ? 0 : (L >> 1);
        bool ok = true;
        {
            const int4* m4 = (const int4*)(mrow + t0);
            #pragma unroll 4
            for (int i = 0; i < 16; ++i) {
                const int4 v = m4[gl * 16 + i];
                ok = ok && (v.x > 0) && (v.y > 0) && (v.z > 0) && (v.w > 0);
            }
        }
        const bool masked = !__all(ok ? 1 : 0);
        if (w == 0) run_chain<0>(lp, mrow, trans, L, ml, gl, masked, a, kacc);
        else        run_chain<1>(lp, mrow, trans, L, ml, gl, masked, a, kacc);
        if (w == 1) {
            #pragma unroll
            for (int i = 0; i < 16; ++i) zfin[l][i] = a[i];
            if (l < 16) kbuf[l] = kacc;
        }
    }

    __syncthreads();

    // ---------------- combine (fwd wave): logZ = (kF+kB)ln2 + log(sum a*z) ----
    if (w == 0) {
        float prod = 0.f;
        #pragma unroll
        for (int i = 0; i < 16; ++i) prod += a[i] * zfin[l][i];
        prod += __shfl_xor(prod, 16);
        prod += __shfl_xor(prod, 32);
        if (l < 16) {
            const float logZ = (float)(kacc + kbuf[l]) * 0.6931471805599453f
                             + __logf(prod);
            out[bg + l] = logZ - (gpart2[0][l] + gpart2[1][l]);
        }
    }
}

extern "C" void kernel_launch(void* const* d_in, const int* in_sizes, int n_in,
                              void* d_out, int out_size, void* d_ws, size_t ws_size,
                              hipStream_t stream) {
    const float* logits = (const float*)d_in[0];
    const int*   tags   = (const int*)d_in[1];
    const int*   mask   = (const int*)d_in[2];
    const float* trans  = (const float*)d_in[3];
    float* out = (float*)d_out;

    const int B = out_size;            // 1024
    const int L = in_sizes[1] / B;     // 512

    crf_mfma_kernel<<<B / 16, 256, 0, stream>>>(logits, tags, mask, trans, out, L);
}

// Round 3
// 277.683 us; speedup vs baseline: 1.0076x; 1.0076x over previous
//
#include <hip/hip_runtime.h>
#include <math.h>

// CRF NLL: out[b] = logZ[b] - gold[b].  B=1024, L=512, T=64.
//
// R7 (passed, 141 us): 16-batches-per-wave MFMA chains (mfma_f32_16x16x32_f16,
//   A=exp(trans) in 8 constant reg fragments; lambda-permutation
//   lambda(c,m)=32(c>>1)+8(m>>2)+4(c&1)+(m&3) makes each lane's 16 D outputs
//   its own next B elements -> zero cross-lane per step). VGPR=80 showed the
//   MachineScheduler's pressure mode SANK the 4-step float4 prefetch down to
//   its exp consumers -> depth-0 pipeline, ~1320 cyc/step of serial latency.
// R8 (NaN): asm-load + hand-counted vmcnt. Fragile: allocator may copy
//   loop-carried asm dest regs before the async load lands (no HW scoreboard),
//   and compiler loads interleave into the vmcnt FIFO. Abandoned.
// R9: R7's verified math + plain compiler-tracked loads pinned with
//   __builtin_amdgcn_sched_barrier(0) after each step's prefetch block.
//   The scheduler cannot cross the barrier, so the loads stay 4 steps (16
//   loads) ahead; SIInsertWaitcnts emits precise counted vmcnt at the exp
//   consumer. Pointer-walk addressing, +-4-row in-bounds overrun (no clamp).
//   Correctness is scheduling-independent (worst case = R7's perf, not NaN).

#define TDIM 64
typedef _Float16 f16;
typedef _Float16 f16x2 __attribute__((ext_vector_type(2)));
typedef _Float16 f16x8 __attribute__((ext_vector_type(8)));
typedef float    f32x4 __attribute__((ext_vector_type(4)));

union B8 { f16x8 v; f16x2 p[4]; };

#define MFMA16(A, B, C) __builtin_amdgcn_mfma_f32_16x16x32_f16((A), (B), (C), 0, 0, 0)

// RTE f16 pair pack (v_cvt_f16_f32 x2 + pack; NOT cvt_pkrtz which is RTZ)
__device__ __forceinline__ f16x2 pk2(float a, float b) {
    f16x2 r; r[0] = (f16)a; r[1] = (f16)b; return r;
}

// One direction's 256-step chain over 16 batches.
// DIR=0: forward (t = 0..L/2-1, t=0 is init).  DIR=1: backward (t = L-1..L/2).
// Lane l: batch = bg + (l&15); holds logical tags lambda(c,4*(l>>4)+r).
template <int DIR>
__device__ __forceinline__ void run_chain(
    const float* __restrict__ lp,    // logits + (bg+ml)*L*64
    const int*   __restrict__ mrow,  // mask   + (bg+ml)*L
    const float* __restrict__ trans,
    int L, int ml, int gl, bool masked,
    float a[16], int& kacc)
{
    // ---- constant A fragments: A_c,kc[m][k] = E(in = 32kc+k, out = lambda(c,m))
    f16x8 Af[4][2];
    #pragma unroll
    for (int c = 0; c < 4; ++c) {
        const int mlog = 32*(c>>1) + 8*(ml>>2) + 4*(c&1) + (ml&3);
        #pragma unroll
        for (int kc = 0; kc < 2; ++kc) {
            B8 t;
            #pragma unroll
            for (int e = 0; e < 8; e += 2) {
                const int k0 = 32*kc + 8*gl + e;
                float x0, x1;
                if (DIR == 0) { x0 = trans[k0*TDIM + mlog];  x1 = trans[(k0+1)*TDIM + mlog]; }
                else          { x0 = trans[mlog*TDIM + k0];  x1 = trans[mlog*TDIM + k0 + 1]; }
                t.p[e>>1] = pk2(__expf(x0), __expf(x1));
            }
            Af[c][kc] = t.v;
        }
    }

    #pragma unroll
    for (int i = 0; i < 16; ++i) a[i] = 1.f;   // bwd: z_{L-1}=1; fwd: dummy
    kacc = 0;

    // per-lane emission base: row t, starting at float 8*gl. Offsets (floats)
    // 0/4/32/36 cover this batch-row slice for logical tags lambda(c,4gl+r).
    const int dstep = (DIR == 0) ? TDIM : -TDIM;
    const float* pp = lp + (size_t)((DIR == 0) ? 0 : (L - 1)) * TDIM + 8 * gl;

    // ---- 4-step register prefetch (16 float4 loads in flight) ----
    float4 Rf[4][4];
    #pragma unroll
    for (int u = 0; u < 4; ++u) {
        Rf[u][0] = *(const float4*)(pp + 0);
        Rf[u][1] = *(const float4*)(pp + 4);
        Rf[u][2] = *(const float4*)(pp + 32);
        Rf[u][3] = *(const float4*)(pp + 36);
        pp += dstep;
    }
    __builtin_amdgcn_sched_barrier(0);

    float Xc[16];
    #pragma unroll
    for (int c = 0; c < 4; ++c) {
        Xc[c*4+0] = __expf(Rf[0][c].x); Xc[c*4+1] = __expf(Rf[0][c].y);
        Xc[c*4+2] = __expf(Rf[0][c].z); Xc[c*4+3] = __expf(Rf[0][c].w);
    }

    const int NS = L >> 1;   // 256 steps
    for (int kb = 0; kb < NS/4; ++kb) {
        #pragma unroll
        for (int u = 0; u < 4; ++u) {
            const int st = 4*kb + u;

            // ---- prefetch step st+4 into slot u (consumed at end of st-1).
            // Overrun past the half (fwd rows 256..259 / bwd 255..252) is
            // in-bounds for L=512. sched_barrier pins the issue point.
            Rf[u][0] = *(const float4*)(pp + 0);
            Rf[u][1] = *(const float4*)(pp + 4);
            Rf[u][2] = *(const float4*)(pp + 32);
            Rf[u][3] = *(const float4*)(pp + 36);
            pp += dstep;
            __builtin_amdgcn_sched_barrier(0);

            float cand[16];
            if (DIR == 0 && st == 0) {
                // init: alpha_0 = exp(logits[:,0,:])
                #pragma unroll
                for (int i = 0; i < 16; ++i) cand[i] = Xc[i];
            } else {
                // B operand: fwd = alpha; bwd = z * X_t
                float bsrc[16];
                #pragma unroll
                for (int i = 0; i < 16; ++i) bsrc[i] = (DIR == 0) ? a[i] : a[i]*Xc[i];
                B8 b0, b1;
                #pragma unroll
                for (int h = 0; h < 4; ++h) {
                    b0.p[h] = pk2(bsrc[2*h],     bsrc[2*h+1]);
                    b1.p[h] = pk2(bsrc[8 + 2*h], bsrc[8 + 2*h+1]);
                }
                f32x4 D0 = {0.f,0.f,0.f,0.f}, D1 = {0.f,0.f,0.f,0.f};
                f32x4 D2 = {0.f,0.f,0.f,0.f}, D3 = {0.f,0.f,0.f,0.f};
                D0 = MFMA16(Af[0][0], b0.v, D0); D0 = MFMA16(Af[0][1], b1.v, D0);
                D1 = MFMA16(Af[1][0], b0.v, D1); D1 = MFMA16(Af[1][1], b1.v, D1);
                D2 = MFMA16(Af[2][0], b0.v, D2); D2 = MFMA16(Af[2][1], b1.v, D2);
                D3 = MFMA16(Af[3][0], b0.v, D3); D3 = MFMA16(Af[3][1], b1.v, D3);
                if (DIR == 0) {
                    #pragma unroll
                    for (int r = 0; r < 4; ++r) {
                        cand[r]      = D0[r] * Xc[r];
                        cand[4 + r]  = D1[r] * Xc[4 + r];
                        cand[8 + r]  = D2[r] * Xc[8 + r];
                        cand[12 + r] = D3[r] * Xc[12 + r];
                    }
                } else {
                    #pragma unroll
                    for (int r = 0; r < 4; ++r) {
                        cand[r] = D0[r]; cand[4+r] = D1[r];
                        cand[8+r] = D2[r]; cand[12+r] = D3[r];
                    }
                }
                if (masked) {               // generic fallback (mask==1 skips)
                    const int t = (DIR == 0) ? st : (L - 1 - st);
                    const int m = mrow[t];
                    #pragma unroll
                    for (int i = 0; i < 16; ++i) cand[i] = (m > 0) ? cand[i] : a[i];
                }
            }

            // consume step st+1's rows (oldest in flight -> compiler emits a
            // counted vmcnt here); exp overlaps this step's MFMA tail
            const int un = (u + 1) & 3;
            float Xn[16];
            #pragma unroll
            for (int c = 0; c < 4; ++c) {
                Xn[c*4+0] = __expf(Rf[un][c].x); Xn[c*4+1] = __expf(Rf[un][c].y);
                Xn[c*4+2] = __expf(Rf[un][c].z); Xn[c*4+3] = __expf(Rf[un][c].w);
            }

            // power-of-2 renorm: ref = logical tag 0 of this batch (lane ml)
            {
                const float ref = __shfl(cand[0], ml);
                const int eb = (__float_as_int(ref) >> 23) & 255;
                kacc += eb - 117;                                // target 2^-10
                const float s = __int_as_float((unsigned)(244 - eb) << 23);
                #pragma unroll
                for (int i = 0; i < 16; ++i) a[i] = cand[i] * s;
            }
            #pragma unroll
            for (int i = 0; i < 16; ++i) Xc[i] = Xn[i];
        }
    }
}

__global__ __launch_bounds__(256, 1) void crf_mfma_kernel(
    const float* __restrict__ logits,  // [B, L, 64]
    const int*   __restrict__ tags,    // [B, L]
    const int*   __restrict__ mask,    // [B, L]
    const float* __restrict__ trans,   // [64, 64]
    float* __restrict__ out,           // [B]
    int L)
{
    const int tid = threadIdx.x;
    const int w   = tid >> 6;          // 0 fwd chain, 1 bwd chain, 2/3 gold
    const int l   = tid & 63;
    const int ml  = l & 15;            // batch within group
    const int gl  = l >> 4;            // lane group
    const int bg  = blockIdx.x * 16;
    const int bi  = bg + ml;

    __shared__ __align__(16) float zfin[64][16];   // bwd final state
    __shared__ float gpart2[2][16];
    __shared__ int   kbuf[16];

    float a[16];
    int   kacc = 0;

    if (w >= 2) {
        // ---------------- gold score, half [t0, t0+L/2) ----------------
        const int t0 = (w - 2) * (L >> 1);
        const int*   tb  = tags + (size_t)bi * L;
        const int*   mb  = mask + (size_t)bi * L;
        const float* lbg = logits + (size_t)bi * L * TDIM;
        float gs = 0.f;
        #pragma unroll 4
        for (int i = 0; i < (L >> 3); ++i) {       // L/2 positions / 4 lanes
            const int t  = t0 + gl + 4*i;
            const int tg = tb[t];
            const float mk = (float)mb[t];
            const float em = lbg[(size_t)t * TDIM + tg];
            const float tr = (t > 0) ? trans[tb[t-1] * TDIM + tg] : 0.f;
            gs += mk * (em + tr);
        }
        gs += __shfl_xor(gs, 16);
        gs += __shfl_xor(gs, 32);
        if (l < 16) gpart2[w - 2][l] = gs;
    } else {
        // ---------------- recurrence chains ----------------
        const float* lp   = logits + (size_t)bi * L * TDIM;
        const int*   mrow = mask + (size_t)bi * L;
        // fast-path detection: all-ones mask in this wave's half?
        const int t0 = (w == 0) ? 0 : (L >> 1);
        bool ok = true;
        {
            const int4* m4 = (const int4*)(mrow + t0);
            #pragma unroll 4
            for (int i = 0; i < 16; ++i) {
                const int4 v = m4[gl * 16 + i];
                ok = ok && (v.x > 0) && (v.y > 0) && (v.z > 0) && (v.w > 0);
            }
        }
        const bool masked = !__all(ok ? 1 : 0);
        if (w == 0) run_chain<0>(lp, mrow, trans, L, ml, gl, masked, a, kacc);
        else        run_chain<1>(lp, mrow, trans, L, ml, gl, masked, a, kacc);
        if (w == 1) {
            #pragma unroll
            for (int i = 0; i < 16; ++i) zfin[l][i] = a[i];
            if (l < 16) kbuf[l] = kacc;
        }
    }

    __syncthreads();

    // ---------------- combine: logZ = (kF+kB)ln2 + log(sum a*z) ----
    if (w == 0) {
        float prod = 0.f;
        #pragma unroll
        for (int i = 0; i < 16; ++i) prod += a[i] * zfin[l][i];
        prod += __shfl_xor(prod, 16);
        prod += __shfl_xor(prod, 32);
        if (l < 16) {
            const float logZ = (float)(kacc + kbuf[l]) * 0.6931471805599453f
                             + __logf(prod);
            out[bg + l] = logZ - (gpart2[0][l] + gpart2[1][l]);
        }
    }
}

extern "C" void kernel_launch(void* const* d_in, const int* in_sizes, int n_in,
                              void* d_out, int out_size, void* d_ws, size_t ws_size,
                              hipStream_t stream) {
    const float* logits = (const float*)d_in[0];
    const int*   tags   = (const int*)d_in[1];
    const int*   mask   = (const int*)d_in[2];
    const float* trans  = (const float*)d_in[3];
    float* out = (float*)d_out;

    const int B = out_size;            // 1024
    const int L = in_sizes[1] / B;     // 512

    crf_mfma_kernel<<<B / 16, 256, 0, stream>>>(logits, tags, mask, trans, out, L);
}

// Round 5
// 272.093 us; speedup vs baseline: 1.0283x; 1.0205x over previous
//
#include <hip/hip_runtime.h>
#include <math.h>

// CRF NLL: out[b] = logZ[b] - gold[b].  B=1024, L=512, T=64.
//
// R7 (141us, pass): 16-batch-per-wave MFMA chains; compiler sank the register
//   prefetch -> ~1320 cyc/step serial HBM latency. R8/R9: register-destination
//   pipelines are uncontrollable at HIP level (NaN / collapsed).
// R10 (NaN): LDS staging via global_load_lds, superstep=8 steps, dbuf,
//   counted vmcnt(32). BUG: used imm offsets 0/16/128/144 on the DMAs with
//   distinct LDS plane bases. CDNA's lds-variant adds the imm offset to the
//   LDS address too (LDS = M0 + offset + lane*16), so planes 1-3 landed
//   shifted (+16/+128/+144); plane 3 overflowed into the next slot ->
//   garbage -> exp -> inf -> NaN. (m97/m201 work with nonzero offsets only
//   because their LDS mirrors the global walk linearly.)
// R11: offset=0 on EVERY DMA; the 0/16/128/144 displacements move into the
//   per-lane GLOBAL pointer (LDS dest = M0 + lane*16 under either semantics).
//   All staging reads via explicit address_space(3) pointers -> ds_read_b128
//   (lgkm-only), so the vmcnt FIFO provably contains only our staging DMAs
//   and the counted vmcnt(32) per superstep stays exact. Compute math
//   identical to verified R7 (lambda-permuted MFMA fragments, pow2 renorm,
//   fwd/bwd split, gold waves, combine).

#define TDIM 64
typedef _Float16 f16;
typedef _Float16 f16x2 __attribute__((ext_vector_type(2)));
typedef _Float16 f16x8 __attribute__((ext_vector_type(8)));
typedef float    f32x4 __attribute__((ext_vector_type(4)));
typedef float    fv4   __attribute__((ext_vector_type(4)));

union B8 { f16x8 v; f16x2 p[4]; };

#define MFMA16(A, B, C) __builtin_amdgcn_mfma_f32_16x16x32_f16((A), (B), (C), 0, 0, 0)

typedef __attribute__((address_space(3))) char       lds_char;
typedef __attribute__((address_space(3))) const fv4  lds_cfv4;
typedef __attribute__((address_space(1))) const char g1_char;

// staging geometry: [wave][buf p][slot u][plane c][lane*16B]
#define PLANE_STRIDE 1024
#define SLOT_STRIDE  4096
#define BUF_STRIDE   32768
#define WV_STRIDE    65536
#define BITMAP_OFF   131072
#define SMEM_BYTES   132096

// RTE f16 pair pack (v_cvt_f16_f32 x2 + pack; NOT cvt_pkrtz which is RTZ)
__device__ __forceinline__ f16x2 pk2(float a, float b) {
    f16x2 r; r[0] = (f16)a; r[1] = (f16)b; return r;
}

// stage one slot (4 planes) for row at pp; ALL DMAs offset=0, displacements
// in the global pointer. LDS dest = uniform plane base + lane*16.
__device__ __forceinline__ void stage_slot(const float* pp, char* slotbase) {
    __builtin_amdgcn_global_load_lds((g1_char*)(pp + 0),  (lds_char*)(slotbase + 0*PLANE_STRIDE), 16, 0, 0);
    __builtin_amdgcn_global_load_lds((g1_char*)(pp + 4),  (lds_char*)(slotbase + 1*PLANE_STRIDE), 16, 0, 0);
    __builtin_amdgcn_global_load_lds((g1_char*)(pp + 32), (lds_char*)(slotbase + 2*PLANE_STRIDE), 16, 0, 0);
    __builtin_amdgcn_global_load_lds((g1_char*)(pp + 36), (lds_char*)(slotbase + 3*PLANE_STRIDE), 16, 0, 0);
}

// One direction's H-step chain over 16 batches.
// DIR=0: forward (t = 0..H-1, t=0 is init).  DIR=1: backward (t = L-1..H).
template <int DIR>
__device__ __forceinline__ void run_chain(
    const float* __restrict__ logits0,   // logits + bg*L*64
    const int*   __restrict__ mask0,     // mask   + bg*L
    const float* __restrict__ trans,
    char* smem, int w, int l, int L, bool masked,
    float a[16], int& kacc)
{
    const int ml = l & 15;               // batch within group
    const int gl = l >> 4;               // lane group
    const int H  = L >> 1;

    // ---- constant A fragments: A_c,kc[m][k] = E(in = 32kc+k, out = lambda(c,m))
    f16x8 Af[4][2];
    #pragma unroll
    for (int c = 0; c < 4; ++c) {
        const int mlog = 32*(c>>1) + 8*(ml>>2) + 4*(c&1) + (ml&3);
        #pragma unroll
        for (int kc = 0; kc < 2; ++kc) {
            B8 t;
            #pragma unroll
            for (int e = 0; e < 8; e += 2) {
                const int k0 = 32*kc + 8*gl + e;
                float x0, x1;
                if (DIR == 0) { x0 = trans[k0*TDIM + mlog];  x1 = trans[(k0+1)*TDIM + mlog]; }
                else          { x0 = trans[mlog*TDIM + k0];  x1 = trans[mlog*TDIM + k0 + 1]; }
                t.p[e>>1] = pk2(__expf(x0), __expf(x1));
            }
            Af[c][kc] = t.v;
        }
    }

    // ---- mask bitmap into LDS (cold path; in-loop mask reads are DS ops so
    // the vmcnt FIFO holds ONLY staging DMAs)
    unsigned* mwv = (unsigned*)(smem + BITMAP_OFF + w * 512);
    const int t0m = DIR ? H : 0;
    const int WPB = H >> 5;              // words per batch (8 for L=512)
    if (masked) {
        for (int flat = l; flat < 16 * WPB; flat += 64) {
            const int mb = flat / WPB, w8 = flat - mb * WPB;
            unsigned word = 0;
            const int* mp = mask0 + (size_t)mb * L + t0m + 32 * w8;
            for (int j = 0; j < 32; ++j) word |= (mp[j] > 0 ? 1u : 0u) << j;
            mwv[flat] = word;
        }
    }

    #pragma unroll
    for (int i = 0; i < 16; ++i) a[i] = 1.f;   // bwd: z_{L-1}=1; fwd: dummy
    kacc = 0;

    char* stg = smem + w * WV_STRIDE;          // this wave's staging
    char* rb0 = stg + 16 * l;                  // lane read base (own 16B slots)
    // per-lane global src: batch (bg+ml), row walk, floats 8gl + {0,4,32,36}
    const float* pp = logits0 + ((size_t)ml * L + (DIR ? (L - 1) : 0)) * TDIM + 8 * gl;
    const int drow = DIR ? -TDIM : TDIM;

    // wall: all prior loads (trans/detect/bitmap) consumed before DMAs issue,
    // so the vmcnt FIFO from here on contains staging DMAs only.
    __builtin_amdgcn_sched_barrier(0);

    // ---- prologue: chunks 0 (buf0) and 1 (buf1), 64 DMAs
    #pragma unroll
    for (int cpre = 0; cpre < 2; ++cpre) {
        char* cb = stg + cpre * BUF_STRIDE;
        #pragma unroll
        for (int u = 0; u < 8; ++u) {
            stage_slot(pp, cb + u * SLOT_STRIDE);
            pp += drow;
        }
    }

    float Xn[16], Xc[16];
    fv4 q[4];
    const int NSS = H >> 3;                    // 32 supersteps
    for (int S = 0; S < NSS; ++S) {
        char* crb = rb0 + (S & 1) * BUF_STRIDE;
        char* cwb = stg + (S & 1) * BUF_STRIDE;

        // drain oldest chunk (exactly counted: 64 outstanding -> 32)
        asm volatile("s_waitcnt vmcnt(32)" ::: "memory");
        __builtin_amdgcn_sched_barrier(0);

        // slot 0 -> Xn (data for step 8S); explicit AS3 reads = ds_read_b128
        q[0] = *(lds_cfv4*)(crb + 0 * PLANE_STRIDE);
        q[1] = *(lds_cfv4*)(crb + 1 * PLANE_STRIDE);
        q[2] = *(lds_cfv4*)(crb + 2 * PLANE_STRIDE);
        q[3] = *(lds_cfv4*)(crb + 3 * PLANE_STRIDE);
        #pragma unroll
        for (int c = 0; c < 4; ++c) {
            #pragma unroll
            for (int r = 0; r < 4; ++r) Xn[c*4 + r] = __expf(q[c][r]);
        }

        #pragma unroll
        for (int u = 0; u < 8; ++u) {
            #pragma unroll
            for (int i = 0; i < 16; ++i) Xc[i] = Xn[i];
            const int st = 8 * S + u;

            if (u < 7) {   // prefetch next slot's raw rows (lgkm-tracked)
                q[0] = *(lds_cfv4*)(crb + (u+1)*SLOT_STRIDE + 0*PLANE_STRIDE);
                q[1] = *(lds_cfv4*)(crb + (u+1)*SLOT_STRIDE + 1*PLANE_STRIDE);
                q[2] = *(lds_cfv4*)(crb + (u+1)*SLOT_STRIDE + 2*PLANE_STRIDE);
                q[3] = *(lds_cfv4*)(crb + (u+1)*SLOT_STRIDE + 3*PLANE_STRIDE);
            }

            float cand[16];
            if (DIR == 0 && st == 0) {
                // init: alpha_0 = exp(logits[:,0,:])
                #pragma unroll
                for (int i = 0; i < 16; ++i) cand[i] = Xc[i];
            } else {
                // B operand: fwd = alpha; bwd = z * X_t
                float bsrc[16];
                #pragma unroll
                for (int i = 0; i < 16; ++i) bsrc[i] = (DIR == 0) ? a[i] : a[i] * Xc[i];
                B8 b0, b1;
                #pragma unroll
                for (int h = 0; h < 4; ++h) {
                    b0.p[h] = pk2(bsrc[2*h],     bsrc[2*h+1]);
                    b1.p[h] = pk2(bsrc[8 + 2*h], bsrc[8 + 2*h+1]);
                }
                f32x4 D0 = {0.f,0.f,0.f,0.f}, D1 = {0.f,0.f,0.f,0.f};
                f32x4 D2 = {0.f,0.f,0.f,0.f}, D3 = {0.f,0.f,0.f,0.f};
                D0 = MFMA16(Af[0][0], b0.v, D0); D0 = MFMA16(Af[0][1], b1.v, D0);
                D1 = MFMA16(Af[1][0], b0.v, D1); D1 = MFMA16(Af[1][1], b1.v, D1);
                D2 = MFMA16(Af[2][0], b0.v, D2); D2 = MFMA16(Af[2][1], b1.v, D2);
                D3 = MFMA16(Af[3][0], b0.v, D3); D3 = MFMA16(Af[3][1], b1.v, D3);
                if (DIR == 0) {
                    #pragma unroll
                    for (int r = 0; r < 4; ++r) {
                        cand[r]      = D0[r] * Xc[r];
                        cand[4 + r]  = D1[r] * Xc[4 + r];
                        cand[8 + r]  = D2[r] * Xc[8 + r];
                        cand[12 + r] = D3[r] * Xc[12 + r];
                    }
                } else {
                    #pragma unroll
                    for (int r = 0; r < 4; ++r) {
                        cand[r] = D0[r]; cand[4+r] = D1[r];
                        cand[8+r] = D2[r]; cand[12+r] = D3[r];
                    }
                }
                if (masked) {   // cold fallback; LDS bitmap read (lgkm)
                    const int dt = DIR ? (H - 1 - st) : st;
                    const unsigned wd = mwv[ml * WPB + (dt >> 5)];
                    const int mb = (wd >> (dt & 31)) & 1;
                    #pragma unroll
                    for (int i = 0; i < 16; ++i) cand[i] = mb ? cand[i] : a[i];
                }
            }

            if (u < 7) {   // exp for step st+1 overlaps this step's MFMA tail
                #pragma unroll
                for (int c = 0; c < 4; ++c) {
                    #pragma unroll
                    for (int r = 0; r < 4; ++r) Xn[c*4 + r] = __expf(q[c][r]);
                }
            }

            // power-of-2 renorm: ref = logical tag 0 of this batch (lane ml)
            {
                const float ref = __shfl(cand[0], ml);
                const int eb = (__float_as_int(ref) >> 23) & 255;
                kacc += eb - 117;                                 // target 2^-10
                const float s = __int_as_float((unsigned)(244 - eb) << 23);
                #pragma unroll
                for (int i = 0; i < 16; ++i) a[i] = cand[i] * s;
            }
        }

        // refill this parity buffer with chunk S+2 (issued LAST so in-flight
        // DMAs during compute are always >= 1 superstep old). Rows overrun
        // past the half by <=16: in-bounds for both directions (L=512 full).
        #pragma unroll
        for (int u = 0; u < 8; ++u) {
            stage_slot(pp, cwb + u * SLOT_STRIDE);
            pp += drow;
        }
    }

    // drain dangling tail DMAs before any LDS reuse
    asm volatile("s_waitcnt vmcnt(0)" ::: "memory");
}

__global__ __launch_bounds__(256, 1) void crf_mfma_kernel(
    const float* __restrict__ logits,  // [B, L, 64]
    const int*   __restrict__ tags,    // [B, L]
    const int*   __restrict__ mask,    // [B, L]
    const float* __restrict__ trans,   // [64, 64]
    float* __restrict__ out,           // [B]
    int L)
{
    const int tid = threadIdx.x;
    const int w   = tid >> 6;          // 0 fwd chain, 1 bwd chain, 2/3 gold
    const int l   = tid & 63;
    const int ml  = l & 15;
    const int gl  = l >> 4;
    const int bg  = blockIdx.x * 16;
    const int bi  = bg + ml;
    const int H   = L >> 1;

    __shared__ __align__(16) char smem[SMEM_BYTES];

    const float* logits0 = logits + (size_t)bg * L * TDIM;
    const int*   mask0   = mask + (size_t)bg * L;

    float a[16];
    int   kacc = 0;
    float gs   = 0.f;

    if (w >= 2) {
        // ---------------- gold score, half [t0, t0+H) ----------------
        const int t0 = (w - 2) * H;
        const int*   tb  = tags + (size_t)bi * L;
        const int*   mb  = mask + (size_t)bi * L;
        const float* lbg = logits + (size_t)bi * L * TDIM;
        #pragma unroll 4
        for (int i = 0; i < (L >> 3); ++i) {       // H positions / 4 lanes
            const int t  = t0 + gl + 4 * i;
            const int tg = tb[t];
            const float mk = (float)mb[t];
            const float em = lbg[(size_t)t * TDIM + tg];
            const float tr = (t > 0) ? trans[tb[t-1] * TDIM + tg] : 0.f;
            gs += mk * (em + tr);
        }
        gs += __shfl_xor(gs, 16);
        gs += __shfl_xor(gs, 32);
    } else {
        // fast-path detection: all-ones mask in this wave's half?
        const int t0d = (w == 0) ? 0 : H;
        bool ok = true;
        {
            const int4* m4 = (const int4*)(mask0 + (size_t)ml * L + t0d);
            #pragma unroll 4
            for (int i = 0; i < (H >> 4); ++i) {
                const int4 v = m4[gl * (H >> 4) + i];
                ok = ok && (v.x > 0) && (v.y > 0) && (v.z > 0) && (v.w > 0);
            }
        }
        const bool masked = !__all(ok ? 1 : 0);
        if (w == 0) run_chain<0>(logits0, mask0, trans, smem, w, l, L, masked, a, kacc);
        else        run_chain<1>(logits0, mask0, trans, smem, w, l, L, masked, a, kacc);
    }

    __syncthreads();

    // staging LDS is drained; carve combine buffers out of wave0's area
    float* zfin = (float*)smem;                       // [64][16]
    float (*gpart2)[16] = (float(*)[16])(smem + 4096);
    int*   kbuf = (int*)(smem + 4224);

    if (w == 1) {
        #pragma unroll
        for (int i = 0; i < 16; ++i) zfin[l * 16 + i] = a[i];
        if (l < 16) kbuf[l] = kacc;
    }
    if (w >= 2 && l < 16) gpart2[w - 2][l] = gs;

    __syncthreads();

    // ---------------- combine: logZ = (kF+kB)ln2 + log(sum a*z) ----
    if (w == 0) {
        float prod = 0.f;
        #pragma unroll
        for (int i = 0; i < 16; ++i) prod += a[i] * zfin[l * 16 + i];
        prod += __shfl_xor(prod, 16);
        prod += __shfl_xor(prod, 32);
        if (l < 16) {
            const float logZ = (float)(kacc + kbuf[l]) * 0.6931471805599453f
                             + __logf(prod);
            out[bg + l] = logZ - (gpart2[0][l] + gpart2[1][l]);
        }
    }
}

extern "C" void kernel_launch(void* const* d_in, const int* in_sizes, int n_in,
                              void* d_out, int out_size, void* d_ws, size_t ws_size,
                              hipStream_t stream) {
    const float* logits = (const float*)d_in[0];
    const int*   tags   = (const int*)d_in[1];
    const int*   mask   = (const int*)d_in[2];
    const float* trans  = (const float*)d_in[3];
    float* out = (float*)d_out;

    const int B = out_size;            // 1024
    const int L = in_sizes[1] / B;     // 512

    crf_mfma_kernel<<<B / 16, 256, 0, stream>>>(logits, tags, mask, trans, out, L);
}